// Round 1
// baseline (267.480 us; speedup 1.0000x reference)
//
#include <hip/hip_runtime.h>
#include <hip/hip_bf16.h>
#include <stdint.h>
#include <math.h>

#define EPS_CELL 1e-6f
#define LN_EPS   1e-5f

typedef short short8 __attribute__((ext_vector_type(8)));
typedef float f32x4 __attribute__((ext_vector_type(4)));

__device__ __forceinline__ unsigned short f2bf(float f) {
    union { float f; uint32_t u; } v; v.f = f;
    uint32_t r = v.u + 0x7FFFu + ((v.u >> 16) & 1u);  // round-to-nearest-even
    return (unsigned short)(r >> 16);
}
__device__ __forceinline__ float bfbits2f(uint32_t hi16_in_place) {
    union { uint32_t u; float f; } v; v.u = hi16_in_place;
    return v.f;
}

// ---------------------------------------------------------------- cast f32->bf16
__global__ __launch_bounds__(256) void cast_f32_bf16(const float* __restrict__ in,
                                                     unsigned short* __restrict__ out,
                                                     int n) {
    int i = (blockIdx.x * 256 + threadIdx.x) * 8;
    if (i >= n) return;
    const float4* p = (const float4*)(in + i);
    float4 a = p[0], b = p[1];
    uint4 r;
    r.x = (uint32_t)f2bf(a.x) | ((uint32_t)f2bf(a.y) << 16);
    r.y = (uint32_t)f2bf(a.z) | ((uint32_t)f2bf(a.w) << 16);
    r.z = (uint32_t)f2bf(b.x) | ((uint32_t)f2bf(b.y) << 16);
    r.w = (uint32_t)f2bf(b.z) | ((uint32_t)f2bf(b.w) << 16);
    *(uint4*)(out + i) = r;
}

// ---------------------------------------------------------------- GEMM: C = A[M,K] * B[N,K]^T + bias, bf16 in, bf16 out
// m97 structure: 128x128 tile, BK=64, 4 waves (2x2), global_load_lds width 16.
template<int K>
__global__ __launch_bounds__(256) void gemm_bt_bias(
        const unsigned short* __restrict__ A,
        const unsigned short* __restrict__ Bm,
        const float* __restrict__ bias,
        unsigned short* __restrict__ C,
        int M, int N) {
    constexpr int BK = 64;
    __shared__ unsigned short As[128 * BK];
    __shared__ unsigned short Bs[128 * BK];

    const int t    = threadIdx.x;
    const int lane = t & 63;
    const int w    = t >> 6;
    const int ln   = lane & 15;
    const int hi   = lane >> 4;
    const int wr   = w >> 1, wc = w & 1;
    const int m0   = blockIdx.y * 128, n0 = blockIdx.x * 128;

    f32x4 acc[4][4] = {};

    for (int k0 = 0; k0 < K; k0 += BK) {
        // stage A tile: 128 rows x 64 cols bf16 = 16 KiB, 4 issues x 256 thr x 16B
#pragma unroll
        for (int i = 0; i < 4; ++i) {
            int c   = i * 256 + t;
            int row = c >> 3;
            int col = (c & 7) * 8;
            __builtin_amdgcn_global_load_lds(
                (const __attribute__((address_space(1))) void*)(A + (size_t)(m0 + row) * K + (k0 + col)),
                (__attribute__((address_space(3))) void*)(As + (size_t)(i * 256 + w * 64) * 8),
                16, 0, 0);
        }
#pragma unroll
        for (int i = 0; i < 4; ++i) {
            int c   = i * 256 + t;
            int row = c >> 3;
            int col = (c & 7) * 8;
            __builtin_amdgcn_global_load_lds(
                (const __attribute__((address_space(1))) void*)(Bm + (size_t)(n0 + row) * K + (k0 + col)),
                (__attribute__((address_space(3))) void*)(Bs + (size_t)(i * 256 + w * 64) * 8),
                16, 0, 0);
        }
        __syncthreads();  // drains vmcnt before barrier

        short8 af[2][4], bfr[2][4];
#pragma unroll
        for (int kk = 0; kk < 2; ++kk) {
#pragma unroll
            for (int m = 0; m < 4; ++m) {
                af[kk][m]  = *(const short8*)&As[(wr * 64 + m * 16 + ln) * BK + kk * 32 + hi * 8];
                bfr[kk][m] = *(const short8*)&Bs[(wc * 64 + m * 16 + ln) * BK + kk * 32 + hi * 8];
            }
        }
#pragma unroll
        for (int kk = 0; kk < 2; ++kk)
#pragma unroll
            for (int m = 0; m < 4; ++m)
#pragma unroll
                for (int n = 0; n < 4; ++n)
                    acc[m][n] = __builtin_amdgcn_mfma_f32_16x16x32_bf16(
                        af[kk][m], bfr[kk][n], acc[m][n], 0, 0, 0);
        __syncthreads();
    }

    // epilogue: D mapping col=lane&15, row=(lane>>4)*4+reg  [verified m89/m91]
#pragma unroll
    for (int n = 0; n < 4; ++n) {
        int col  = n0 + wc * 64 + n * 16 + ln;
        float bv = bias[col];
#pragma unroll
        for (int m = 0; m < 4; ++m) {
            int rowb = m0 + wr * 64 + m * 16 + hi * 4;
#pragma unroll
            for (int r = 0; r < 4; ++r) {
                C[(size_t)(rowb + r) * N + col] = f2bf(acc[m][n][r] + bv);
            }
        }
    }
}

// ---------------------------------------------------------------- block reduce (256 thr = 4 waves)
template<int NV>
__device__ __forceinline__ void block_reduce_sum(float* v, float* sred) {
    const int lane = threadIdx.x & 63;
    const int w    = threadIdx.x >> 6;
#pragma unroll
    for (int i = 0; i < NV; ++i) {
        float s = v[i];
#pragma unroll
        for (int o = 32; o > 0; o >>= 1) s += __shfl_down(s, o, 64);
        if (lane == 0) sred[i * 4 + w] = s;
    }
    __syncthreads();
#pragma unroll
    for (int i = 0; i < NV; ++i)
        v[i] = sred[i * 4 + 0] + sred[i * 4 + 1] + sred[i * 4 + 2] + sred[i * 4 + 3];
    __syncthreads();  // sred reusable afterwards
}

// ---------------------------------------------------------------- fused row-wise cell
// one block (256 thr) per batch row; U,V are pre-LN gate activations [B,4096] bf16
__global__ __launch_bounds__(256) void fused_cell(
        const unsigned short* __restrict__ U, const unsigned short* __restrict__ V,
        const float* __restrict__ c_prev,
        const float* __restrict__ g_in, const float* __restrict__ b_in,
        const float* __restrict__ g_hu, const float* __restrict__ b_hu,
        const float* __restrict__ g_c,  const float* __restrict__ b_c,
        const float* __restrict__ g_h,  const float* __restrict__ b_h,
        float* __restrict__ out_h, float* __restrict__ out_c) {
    __shared__ __align__(16) float sg[4096];
    __shared__ float sred[16];
    const int r = blockIdx.x;
    const int t = threadIdx.x;
    const size_t rowG = (size_t)r * 4096;
    const size_t rowH = (size_t)r * 1024;

    // --- load u,v (16 contiguous bf16 each), accumulate stats
    float uf[16], vf[16];
    {
        const uint4* pu = (const uint4*)(U + rowG + (size_t)t * 16);
        const uint4* pv = (const uint4*)(V + rowG + (size_t)t * 16);
        uint4 u0 = pu[0], u1 = pu[1], v0 = pv[0], v1 = pv[1];
        uint32_t uw[8] = {u0.x, u0.y, u0.z, u0.w, u1.x, u1.y, u1.z, u1.w};
        uint32_t vw[8] = {v0.x, v0.y, v0.z, v0.w, v1.x, v1.y, v1.z, v1.w};
#pragma unroll
        for (int j = 0; j < 8; ++j) {
            uf[2 * j]     = bfbits2f(uw[j] << 16);
            uf[2 * j + 1] = bfbits2f(uw[j] & 0xFFFF0000u);
            vf[2 * j]     = bfbits2f(vw[j] << 16);
            vf[2 * j + 1] = bfbits2f(vw[j] & 0xFFFF0000u);
        }
    }
    float red[4] = {0.f, 0.f, 0.f, 0.f};
#pragma unroll
    for (int j = 0; j < 16; ++j) {
        red[0] += uf[j]; red[1] += uf[j] * uf[j];
        red[2] += vf[j]; red[3] += vf[j] * vf[j];
    }
    block_reduce_sum<4>(red, sred);
    const float inv4096 = 1.f / 4096.f;
    float mu_u = red[0] * inv4096, mu_v = red[2] * inv4096;
    float rs_u = rsqrtf(red[1] * inv4096 - mu_u * mu_u + LN_EPS);
    float rs_v = rsqrtf(red[3] * inv4096 - mu_v * mu_v + LN_EPS);

    // --- gates = LN(u)*g1+b1 + LN(v)*g2+b2  -> LDS
#pragma unroll
    for (int j = 0; j < 16; ++j) {
        int idx = t * 16 + j;
        float zu = (uf[j] - mu_u) * rs_u;
        float zv = (vf[j] - mu_v) * rs_v;
        sg[idx] = zu * g_in[idx] + b_in[idx] + zv * g_hu[idx] + b_hu[idx];
    }
    __syncthreads();

    // --- per-segment processing, thread owns 4 elems of each H=1024 segment
    const float4* sg4 = (const float4*)sg;
    float4 gi4 = sg4[0 * 256 + t];
    float4 gf4 = sg4[1 * 256 + t];
    float4 gg4 = sg4[2 * 256 + t];
    float4 go4 = sg4[3 * 256 + t];
    float gi[4] = {gi4.x, gi4.y, gi4.z, gi4.w};
    float gf[4] = {gf4.x, gf4.y, gf4.z, gf4.w};
    float gg[4] = {gg4.x, gg4.y, gg4.z, gg4.w};
    float go[4] = {go4.x, go4.y, go4.z, go4.w};

    red[0] = gi[0] + gi[1] + gi[2] + gi[3];
    red[1] = gf[0] + gf[1] + gf[2] + gf[3];
    block_reduce_sum<2>(red, sred);
    const float inv1024 = 1.f / 1024.f;
    float mi = red[0] * inv1024, mf = red[1] * inv1024;

    float ei[4], ef[4];
#pragma unroll
    for (int q = 0; q < 4; ++q) {
        ei[q] = expf(fminf(fmaxf(gi[q] - mi, -5.f), 5.f));
        ef[q] = expf(fminf(fmaxf(gf[q] - mf, -5.f), 5.f));
    }
    red[0] = ei[0] + ei[1] + ei[2] + ei[3];
    red[1] = ef[0] + ef[1] + ef[2] + ef[3];
    block_reduce_sum<2>(red, sred);
    float inv_si = 1.f / (red[0] + EPS_CELL);
    float inv_sf = 1.f / (red[1] + EPS_CELL);

    const float4* cp4p = (const float4*)(c_prev + rowH);
    float4 cp4 = cp4p[t];
    float cprev[4] = {cp4.x, cp4.y, cp4.z, cp4.w};

    float cpv[4];
#pragma unroll
    for (int q = 0; q < 4; ++q) {
        float in_ = ei[q] * inv_si;
        float fn_ = ef[q] * inv_sf;
        float den = 1.f / (in_ + fn_ + EPS_CELL);
        float i2 = in_ * den, f2 = fn_ * den;
        cpv[q] = f2 * cprev[q] + i2 * tanhf(gg[q]);
    }
    red[0] = cpv[0] + cpv[1] + cpv[2] + cpv[3];
    red[1] = cpv[0] * cpv[0] + cpv[1] * cpv[1] + cpv[2] * cpv[2] + cpv[3] * cpv[3];
    block_reduce_sum<2>(red, sred);
    float mu_c = red[0] * inv1024;
    float rs_c = rsqrtf(red[1] * inv1024 - mu_c * mu_c + LN_EPS);

    float cv[4], th[4];
#pragma unroll
    for (int q = 0; q < 4; ++q) {
        int j = t * 4 + q;
        cv[q] = (cpv[q] - mu_c) * rs_c * g_c[j] + b_c[j];
        th[q] = tanhf(cv[q]);
    }
    {   // write c output
        float4 o; o.x = cv[0]; o.y = cv[1]; o.z = cv[2]; o.w = cv[3];
        *(float4*)(out_c + rowH + (size_t)t * 4) = o;
    }
    red[0] = th[0] + th[1] + th[2] + th[3];
    red[1] = th[0] * th[0] + th[1] * th[1] + th[2] * th[2] + th[3] * th[3];
    block_reduce_sum<2>(red, sred);
    float mu_t = red[0] * inv1024;
    float rs_t = rsqrtf(red[1] * inv1024 - mu_t * mu_t + LN_EPS);

    float hv[4];
#pragma unroll
    for (int q = 0; q < 4; ++q) {
        int j = t * 4 + q;
        float co = (th[q] - mu_t) * rs_t * g_h[j] + b_h[j];
        float so = 1.f / (1.f + expf(-go[q]));
        hv[q] = so * co;
    }
    {
        float4 o; o.x = hv[0]; o.y = hv[1]; o.z = hv[2]; o.w = hv[3];
        *(float4*)(out_h + rowH + (size_t)t * 4) = o;
    }
}

// ---------------------------------------------------------------- launch
extern "C" void kernel_launch(void* const* d_in, const int* in_sizes, int n_in,
                              void* d_out, int out_size, void* d_ws, size_t ws_size,
                              hipStream_t stream) {
    const float* x       = (const float*)d_in[0];
    const float* h_prev  = (const float*)d_in[1];
    const float* c_prev  = (const float*)d_in[2];
    const float* Wx      = (const float*)d_in[3];
    const float* bx      = (const float*)d_in[4];
    const float* Wh      = (const float*)d_in[5];
    const float* bh      = (const float*)d_in[6];
    const float* ln_in_g = (const float*)d_in[7];
    const float* ln_in_b = (const float*)d_in[8];
    const float* ln_hu_g = (const float*)d_in[9];
    const float* ln_hu_b = (const float*)d_in[10];
    const float* ln_c_g  = (const float*)d_in[11];
    const float* ln_c_b  = (const float*)d_in[12];
    const float* ln_h_g  = (const float*)d_in[13];
    const float* ln_h_b  = (const float*)d_in[14];

    const int B = 8192, Din = 512, H = 1024, G = 4096;

    unsigned short* xb  = (unsigned short*)d_ws;                 // B*Din
    unsigned short* hb  = xb  + (size_t)B * Din;                 // B*H
    unsigned short* wxb = hb  + (size_t)B * H;                   // G*Din
    unsigned short* whb = wxb + (size_t)G * Din;                 // G*H
    unsigned short* U   = whb + (size_t)G * H;                   // B*G
    unsigned short* V   = U   + (size_t)B * G;                   // B*G
    // total ws use: 2*(B*Din + B*H + G*Din + G*H + 2*B*G) = 164 MiB

    cast_f32_bf16<<<(B * Din) / 2048, 256, 0, stream>>>(x, xb, B * Din);
    cast_f32_bf16<<<(B * H)   / 2048, 256, 0, stream>>>(h_prev, hb, B * H);
    cast_f32_bf16<<<(G * Din) / 2048, 256, 0, stream>>>(Wx, wxb, G * Din);
    cast_f32_bf16<<<(G * H)   / 2048, 256, 0, stream>>>(Wh, whb, G * H);

    dim3 gg(G / 128, B / 128);
    gemm_bt_bias<512> <<<gg, 256, 0, stream>>>(xb, wxb, bx, U, B, G);
    gemm_bt_bias<1024><<<gg, 256, 0, stream>>>(hb, whb, bh, V, B, G);

    float* out_h = (float*)d_out;
    float* out_c = out_h + (size_t)B * H;
    fused_cell<<<B, 256, 0, stream>>>(U, V, c_prev,
                                      ln_in_g, ln_in_b, ln_hu_g, ln_hu_b,
                                      ln_c_g, ln_c_b, ln_h_g, ln_h_b,
                                      out_h, out_c);
}

// Round 2
// 246.423 us; speedup vs baseline: 1.0855x; 1.0855x over previous
//
#include <hip/hip_runtime.h>
#include <hip/hip_bf16.h>
#include <stdint.h>
#include <math.h>

#define EPS_CELL 1e-6f
#define LN_EPS   1e-5f

typedef short short8 __attribute__((ext_vector_type(8)));
typedef float f32x4 __attribute__((ext_vector_type(4)));
typedef unsigned short ushort;

__device__ __forceinline__ ushort f2bf(float f) {
    union { float f; uint32_t u; } v; v.f = f;
    uint32_t r = v.u + 0x7FFFu + ((v.u >> 16) & 1u);  // round-to-nearest-even
    return (ushort)(r >> 16);
}
__device__ __forceinline__ float bfbits2f(uint32_t hi16_in_place) {
    union { uint32_t u; float f; } v; v.u = hi16_in_place;
    return v.f;
}

// ---------------------------------------------------------------- cast f32->bf16
__global__ __launch_bounds__(256) void cast_f32_bf16(const float* __restrict__ in,
                                                     ushort* __restrict__ out,
                                                     int n) {
    int i = (blockIdx.x * 256 + threadIdx.x) * 8;
    if (i >= n) return;
    const float4* p = (const float4*)(in + i);
    float4 a = p[0], b = p[1];
    uint4 r;
    r.x = (uint32_t)f2bf(a.x) | ((uint32_t)f2bf(a.y) << 16);
    r.y = (uint32_t)f2bf(a.z) | ((uint32_t)f2bf(a.w) << 16);
    r.z = (uint32_t)f2bf(b.x) | ((uint32_t)f2bf(b.y) << 16);
    r.w = (uint32_t)f2bf(b.z) | ((uint32_t)f2bf(b.w) << 16);
    *(uint4*)(out + i) = r;
}

// ================================================================ 256x256 8-phase GEMM
// C[M,GN] = A[M,K] * B[GN,K]^T + bias, bf16 in/out.
// 8 waves (2M x 4N), BK=64, double-buffered 128 KiB LDS, T1+T2+T3+T4+T5.
#define BAR()        __builtin_amdgcn_s_barrier()
#define SPRIO(x)     __builtin_amdgcn_s_setprio(x)
#define WAIT_LGKM0() do { asm volatile("s_waitcnt lgkmcnt(0)" ::: "memory"); \
                          __builtin_amdgcn_sched_barrier(0); } while (0)
#define WAIT_VM2()   do { asm volatile("s_waitcnt vmcnt(2)" ::: "memory"); \
                          __builtin_amdgcn_sched_barrier(0); } while (0)

template<int K>
__global__ __launch_bounds__(512, 2) void gemm256_8ph(
        const ushort* __restrict__ Ag,   // [M, K]
        const ushort* __restrict__ Bg,   // [GN, K]
        const float*  __restrict__ bias, // [GN]
        ushort* __restrict__ C,          // [M, GN]
        int M, int GN) {
    constexpr int NT = K / 64;           // K-tiles
    constexpr int NP = NT / 2;           // pair iterations

    __shared__ ushort lds[65536];        // 128 KiB: buf0{A,B} buf1{A,B}, 16384 shorts each

    const int t    = threadIdx.x;        // 0..511
    const int lane = t & 63;
    const int w    = t >> 6;             // 0..7
    const int wr   = w >> 2;             // 0..1 (M half)
    const int wc   = w & 3;              // 0..3 (N quarter)
    const int ln   = lane & 15;
    const int hi   = lane >> 4;          // 0..3
    const int sx   = ln & 7;             // read-side XOR key (row&7)

    // XCD-aware bijective swizzle (gridDim.x = 512, %8==0)
    const int bid = blockIdx.x;
    const int wg  = (bid & 7) * 64 + (bid >> 3);
    const int n0  = (wg & 15) * 256;     // GN/256 = 16
    const int m0  = (wg >> 4) * 256;

    // staging: thread t stages 16B; dst is LINEAR (global_load_lds constraint);
    // the SOURCE column is pre-swizzled so that swizzled reads see linear data.
    const int trow = t >> 3;                          // 0..63 within a 64-row issue
    const int scol = (((t & 7) ^ (trow & 7)) * 8);    // shorts

#define STG_A(buf, j, kb) __builtin_amdgcn_global_load_lds( \
    (const __attribute__((address_space(1))) void*)(Ag + (size_t)(m0 + (j)*64 + trow) * K + (kb) + scol), \
    (__attribute__((address_space(3))) void*)(lds + (buf)*32768 + (j)*4096 + t*8), 16, 0, 0)
#define STG_B(buf, j, kb) __builtin_amdgcn_global_load_lds( \
    (const __attribute__((address_space(1))) void*)(Bg + (size_t)(n0 + (j)*64 + trow) * K + (kb) + scol), \
    (__attribute__((address_space(3))) void*)(lds + (buf)*32768 + 16384 + (j)*4096 + t*8), 16, 0, 0)

    // swizzled read offsets (shorts): row*64 + ((kk*4+hi)^(row&7))*8, row&7 == ln&7
    const int ca0  = ((0 + hi) ^ sx) * 8;             // kk = 0
    const int ca1  = ((4 + hi) ^ sx) * 8;             // kk = 1
    const int arow = (wr * 128 + ln) * 64;            // + m*1024
    const int brow = (wc * 64 + ln) * 64;             // + n*1024 (+16384 matrix base)

    short8 af[2][4], bf0[2][2], bf1[2][2];
    f32x4  acc[8][4] = {};

#define LD_A(buf, mbase) do { _Pragma("unroll") for (int m = 0; m < 4; ++m) { \
    af[0][m] = *(const short8*)&lds[(buf)*32768 + arow + ((mbase)+m)*1024 + ca0]; \
    af[1][m] = *(const short8*)&lds[(buf)*32768 + arow + ((mbase)+m)*1024 + ca1]; } } while (0)
#define LD_B(dst, buf, nbase) do { _Pragma("unroll") for (int n = 0; n < 2; ++n) { \
    dst[0][n] = *(const short8*)&lds[(buf)*32768 + 16384 + brow + ((nbase)+n)*1024 + ca0]; \
    dst[1][n] = *(const short8*)&lds[(buf)*32768 + 16384 + brow + ((nbase)+n)*1024 + ca1]; } } while (0)
#define MMQ(mb, nb, B_) do { _Pragma("unroll") for (int kk = 0; kk < 2; ++kk) \
    _Pragma("unroll") for (int m = 0; m < 4; ++m) \
    _Pragma("unroll") for (int n = 0; n < 2; ++n) \
        acc[(mb)+m][(nb)+n] = __builtin_amdgcn_mfma_f32_16x16x32_bf16( \
            af[kk][m], B_[kk][n], acc[(mb)+m][(nb)+n], 0, 0, 0); } while (0)

    // ---- prologue: tile0 -> buf0 (8 issues), tile1 B0,B1 -> buf1 (2 issues)
    STG_B(0,0,0); STG_B(0,1,0); STG_B(0,2,0); STG_B(0,3,0);
    STG_A(0,0,0); STG_A(0,2,0); STG_A(0,1,0); STG_A(0,3,0);
    STG_B(1,0,64); STG_B(1,1,64);
    WAIT_VM2(); BAR();

    // ---- main loop: pair p computes tiles 2p (buf0) and 2p+1 (buf1)
    for (int p = 0; p < NP; ++p) {
        const int k1 = (2*p + 1) * 64;              // buf1's tile (this iter)
        const int k2 = ((2*p + 2) & (NT - 1)) * 64; // next buf0 tile (wraps on last iter)
        const int k3 = ((2*p + 3) & (NT - 1)) * 64; // next buf1 tile

        // P1: 12 ds_read, stage buf1 B2,B3
        LD_A(0, 0); LD_B(bf0, 0, 0);
        STG_B(1,2,k1); STG_B(1,3,k1);
        BAR(); WAIT_LGKM0();
        SPRIO(1); MMQ(0,0,bf0); SPRIO(0); BAR();
        // P2: 4 ds_read, stage buf1 A0,A2
        LD_B(bf1, 0, 2);
        STG_A(1,0,k1); STG_A(1,2,k1);
        BAR(); WAIT_LGKM0();
        SPRIO(1); MMQ(0,2,bf1); SPRIO(0); BAR();
        // P3: 8 ds_read, stage buf1 A1,A3  (all buf0 reads done after this phase)
        LD_A(0, 4);
        STG_A(1,1,k1); STG_A(1,3,k1);
        BAR(); WAIT_LGKM0();
        SPRIO(1); MMQ(4,0,bf0); SPRIO(0); BAR();
        // P4: stage buf0 B0,B1 (next tile); counted vmcnt — buf1 fully landed
        STG_B(0,0,k2); STG_B(0,1,k2);
        BAR();
        SPRIO(1); MMQ(4,2,bf1); SPRIO(0);
        WAIT_VM2(); BAR();
        // P5: 12 ds_read (buf1), stage buf0 B2,B3
        LD_A(1, 0); LD_B(bf0, 1, 0);
        STG_B(0,2,k2); STG_B(0,3,k2);
        BAR(); WAIT_LGKM0();
        SPRIO(1); MMQ(0,0,bf0); SPRIO(0); BAR();
        // P6: 4 ds_read, stage buf0 A0,A2
        LD_B(bf1, 1, 2);
        STG_A(0,0,k2); STG_A(0,2,k2);
        BAR(); WAIT_LGKM0();
        SPRIO(1); MMQ(0,2,bf1); SPRIO(0); BAR();
        // P7: 8 ds_read, stage buf0 A1,A3  (all buf1 reads done after this phase)
        LD_A(1, 4);
        STG_A(0,1,k2); STG_A(0,3,k2);
        BAR(); WAIT_LGKM0();
        SPRIO(1); MMQ(4,0,bf0); SPRIO(0); BAR();
        // P8: stage buf1 B0,B1 (tile k3); counted vmcnt — next buf0 fully landed
        STG_B(1,0,k3); STG_B(1,1,k3);
        BAR();
        SPRIO(1); MMQ(4,2,bf1); SPRIO(0);
        WAIT_VM2(); BAR();
    }

    // ---- epilogue: D mapping col=lane&15, row=(lane>>4)*4+reg
#pragma unroll
    for (int n = 0; n < 4; ++n) {
        int col  = n0 + wc * 64 + n * 16 + ln;
        float bv = bias[col];
#pragma unroll
        for (int m = 0; m < 8; ++m) {
            int row = m0 + wr * 128 + m * 16 + hi * 4;
#pragma unroll
            for (int r = 0; r < 4; ++r)
                C[(size_t)(row + r) * GN + col] = f2bf(acc[m][n][r] + bv);
        }
    }
#undef STG_A
#undef STG_B
#undef LD_A
#undef LD_B
#undef MMQ
}

// ---------------------------------------------------------------- block reduce (256 thr = 4 waves)
template<int NV>
__device__ __forceinline__ void block_reduce_sum(float* v, float* sred) {
    const int lane = threadIdx.x & 63;
    const int w    = threadIdx.x >> 6;
#pragma unroll
    for (int i = 0; i < NV; ++i) {
        float s = v[i];
#pragma unroll
        for (int o = 32; o > 0; o >>= 1) s += __shfl_down(s, o, 64);
        if (lane == 0) sred[i * 4 + w] = s;
    }
    __syncthreads();
#pragma unroll
    for (int i = 0; i < NV; ++i)
        v[i] = sred[i * 4 + 0] + sred[i * 4 + 1] + sred[i * 4 + 2] + sred[i * 4 + 3];
    __syncthreads();
}

// ---------------------------------------------------------------- fused row-wise cell
__global__ __launch_bounds__(256) void fused_cell(
        const ushort* __restrict__ U, const ushort* __restrict__ V,
        const float* __restrict__ c_prev,
        const float* __restrict__ g_in, const float* __restrict__ b_in,
        const float* __restrict__ g_hu, const float* __restrict__ b_hu,
        const float* __restrict__ g_c,  const float* __restrict__ b_c,
        const float* __restrict__ g_h,  const float* __restrict__ b_h,
        float* __restrict__ out_h, float* __restrict__ out_c) {
    __shared__ __align__(16) float sg[4096];
    __shared__ float sred[16];
    const int r = blockIdx.x;
    const int t = threadIdx.x;
    const size_t rowG = (size_t)r * 4096;
    const size_t rowH = (size_t)r * 1024;

    float uf[16], vf[16];
    {
        const uint4* pu = (const uint4*)(U + rowG + (size_t)t * 16);
        const uint4* pv = (const uint4*)(V + rowG + (size_t)t * 16);
        uint4 u0 = pu[0], u1 = pu[1], v0 = pv[0], v1 = pv[1];
        uint32_t uw[8] = {u0.x, u0.y, u0.z, u0.w, u1.x, u1.y, u1.z, u1.w};
        uint32_t vw[8] = {v0.x, v0.y, v0.z, v0.w, v1.x, v1.y, v1.z, v1.w};
#pragma unroll
        for (int j = 0; j < 8; ++j) {
            uf[2 * j]     = bfbits2f(uw[j] << 16);
            uf[2 * j + 1] = bfbits2f(uw[j] & 0xFFFF0000u);
            vf[2 * j]     = bfbits2f(vw[j] << 16);
            vf[2 * j + 1] = bfbits2f(vw[j] & 0xFFFF0000u);
        }
    }
    float red[4] = {0.f, 0.f, 0.f, 0.f};
#pragma unroll
    for (int j = 0; j < 16; ++j) {
        red[0] += uf[j]; red[1] += uf[j] * uf[j];
        red[2] += vf[j]; red[3] += vf[j] * vf[j];
    }
    block_reduce_sum<4>(red, sred);
    const float inv4096 = 1.f / 4096.f;
    float mu_u = red[0] * inv4096, mu_v = red[2] * inv4096;
    float rs_u = rsqrtf(red[1] * inv4096 - mu_u * mu_u + LN_EPS);
    float rs_v = rsqrtf(red[3] * inv4096 - mu_v * mu_v + LN_EPS);

#pragma unroll
    for (int j = 0; j < 16; ++j) {
        int idx = t * 16 + j;
        float zu = (uf[j] - mu_u) * rs_u;
        float zv = (vf[j] - mu_v) * rs_v;
        sg[idx] = zu * g_in[idx] + b_in[idx] + zv * g_hu[idx] + b_hu[idx];
    }
    __syncthreads();

    const float4* sg4 = (const float4*)sg;
    float4 gi4 = sg4[0 * 256 + t];
    float4 gf4 = sg4[1 * 256 + t];
    float4 gg4 = sg4[2 * 256 + t];
    float4 go4 = sg4[3 * 256 + t];
    float gi[4] = {gi4.x, gi4.y, gi4.z, gi4.w};
    float gf[4] = {gf4.x, gf4.y, gf4.z, gf4.w};
    float gg[4] = {gg4.x, gg4.y, gg4.z, gg4.w};
    float go[4] = {go4.x, go4.y, go4.z, go4.w};

    red[0] = gi[0] + gi[1] + gi[2] + gi[3];
    red[1] = gf[0] + gf[1] + gf[2] + gf[3];
    block_reduce_sum<2>(red, sred);
    const float inv1024 = 1.f / 1024.f;
    float mi = red[0] * inv1024, mf = red[1] * inv1024;

    float ei[4], ef[4];
#pragma unroll
    for (int q = 0; q < 4; ++q) {
        ei[q] = expf(fminf(fmaxf(gi[q] - mi, -5.f), 5.f));
        ef[q] = expf(fminf(fmaxf(gf[q] - mf, -5.f), 5.f));
    }
    red[0] = ei[0] + ei[1] + ei[2] + ei[3];
    red[1] = ef[0] + ef[1] + ef[2] + ef[3];
    block_reduce_sum<2>(red, sred);
    float inv_si = 1.f / (red[0] + EPS_CELL);
    float inv_sf = 1.f / (red[1] + EPS_CELL);

    const float4* cp4p = (const float4*)(c_prev + rowH);
    float4 cp4 = cp4p[t];
    float cprev[4] = {cp4.x, cp4.y, cp4.z, cp4.w};

    float cpv[4];
#pragma unroll
    for (int q = 0; q < 4; ++q) {
        float in_ = ei[q] * inv_si;
        float fn_ = ef[q] * inv_sf;
        float den = 1.f / (in_ + fn_ + EPS_CELL);
        float i2 = in_ * den, f2 = fn_ * den;
        cpv[q] = f2 * cprev[q] + i2 * tanhf(gg[q]);
    }
    red[0] = cpv[0] + cpv[1] + cpv[2] + cpv[3];
    red[1] = cpv[0] * cpv[0] + cpv[1] * cpv[1] + cpv[2] * cpv[2] + cpv[3] * cpv[3];
    block_reduce_sum<2>(red, sred);
    float mu_c = red[0] * inv1024;
    float rs_c = rsqrtf(red[1] * inv1024 - mu_c * mu_c + LN_EPS);

    float cv[4], th[4];
#pragma unroll
    for (int q = 0; q < 4; ++q) {
        int j = t * 4 + q;
        cv[q] = (cpv[q] - mu_c) * rs_c * g_c[j] + b_c[j];
        th[q] = tanhf(cv[q]);
    }
    {
        float4 o; o.x = cv[0]; o.y = cv[1]; o.z = cv[2]; o.w = cv[3];
        *(float4*)(out_c + rowH + (size_t)t * 4) = o;
    }
    red[0] = th[0] + th[1] + th[2] + th[3];
    red[1] = th[0] * th[0] + th[1] * th[1] + th[2] * th[2] + th[3] * th[3];
    block_reduce_sum<2>(red, sred);
    float mu_t = red[0] * inv1024;
    float rs_t = rsqrtf(red[1] * inv1024 - mu_t * mu_t + LN_EPS);

    float hv[4];
#pragma unroll
    for (int q = 0; q < 4; ++q) {
        int j = t * 4 + q;
        float co = (th[q] - mu_t) * rs_t * g_h[j] + b_h[j];
        float so = 1.f / (1.f + expf(-go[q]));
        hv[q] = so * co;
    }
    {
        float4 o; o.x = hv[0]; o.y = hv[1]; o.z = hv[2]; o.w = hv[3];
        *(float4*)(out_h + rowH + (size_t)t * 4) = o;
    }
}

// ---------------------------------------------------------------- launch
extern "C" void kernel_launch(void* const* d_in, const int* in_sizes, int n_in,
                              void* d_out, int out_size, void* d_ws, size_t ws_size,
                              hipStream_t stream) {
    const float* x       = (const float*)d_in[0];
    const float* h_prev  = (const float*)d_in[1];
    const float* c_prev  = (const float*)d_in[2];
    const float* Wx      = (const float*)d_in[3];
    const float* bx      = (const float*)d_in[4];
    const float* Wh      = (const float*)d_in[5];
    const float* bh      = (const float*)d_in[6];
    const float* ln_in_g = (const float*)d_in[7];
    const float* ln_in_b = (const float*)d_in[8];
    const float* ln_hu_g = (const float*)d_in[9];
    const float* ln_hu_b = (const float*)d_in[10];
    const float* ln_c_g  = (const float*)d_in[11];
    const float* ln_c_b  = (const float*)d_in[12];
    const float* ln_h_g  = (const float*)d_in[13];
    const float* ln_h_b  = (const float*)d_in[14];

    const int B = 8192, Din = 512, H = 1024, G = 4096;

    ushort* xb  = (ushort*)d_ws;                  // B*Din
    ushort* hb  = xb  + (size_t)B * Din;          // B*H
    ushort* wxb = hb  + (size_t)B * H;            // G*Din
    ushort* whb = wxb + (size_t)G * Din;          // G*H
    ushort* U   = whb + (size_t)G * H;            // B*G
    ushort* V   = U   + (size_t)B * G;            // B*G

    cast_f32_bf16<<<(B * Din) / 2048, 256, 0, stream>>>(x, xb, B * Din);
    cast_f32_bf16<<<(B * H)   / 2048, 256, 0, stream>>>(h_prev, hb, B * H);
    cast_f32_bf16<<<(G * Din) / 2048, 256, 0, stream>>>(Wx, wxb, G * Din);
    cast_f32_bf16<<<(G * H)   / 2048, 256, 0, stream>>>(Wh, whb, G * H);

    // grid: (G/256) * (B/256) = 16 * 32 = 512 blocks, 512 threads
    gemm256_8ph<512> <<<dim3(512), 512, 0, stream>>>(xb, wxb, bx, U, B, G);
    gemm256_8ph<1024><<<dim3(512), 512, 0, stream>>>(hb, whb, bh, V, B, G);

    float* out_h = (float*)d_out;
    float* out_c = out_h + (size_t)B * H;
    fused_cell<<<B, 256, 0, stream>>>(U, V, c_prev,
                                      ln_in_g, ln_in_b, ln_hu_g, ln_hu_b,
                                      ln_c_g, ln_c_b, ln_h_g, ln_h_b,
                                      out_h, out_c);
}